// Round 15
// baseline (110.501 us; speedup 1.0000x reference)
//
#include <hip/hip_runtime.h>
#include <hip/hip_bf16.h>
#include <hip/hip_fp16.h>

#define IN_C 512
#define HID_C 128
#define OUT_C 16
#define STILE 8192     // nodes per hist supertile (32KB LDS)
#define SSH  13        // log2(STILE)
#define KCH_H 16       // edge chunks per supertile (hist)
#define NREP 8         // one accumulator replica per XCD

typedef float    f32x4 __attribute__((ext_vector_type(4)));
typedef float    f32x2 __attribute__((ext_vector_type(2)));
typedef int      i32x4 __attribute__((ext_vector_type(4)));
typedef _Float16 h16x2 __attribute__((ext_vector_type(2)));

// Packed f16 global atomic add (global_atomic_pk_add_f16 on CDNA).
__device__ inline void pk_atomic_add_f16(h16x2* addr, h16x2 val) {
#if __has_builtin(__builtin_amdgcn_global_atomic_fadd_v2f16)
    __builtin_amdgcn_global_atomic_fadd_v2f16(addr, val);
#else
    unsigned int* ap = (unsigned int*)addr;
    unsigned int old = *ap, assumed;
    do {
        assumed = old;
        h16x2 cur = __builtin_bit_cast(h16x2, assumed);
        h16x2 nv = cur + val;
        old = atomicCAS(ap, assumed, __builtin_bit_cast(unsigned int, nv));
    } while (old != assumed);
#endif
}

// ---------------------------------------------------------------------------
// K1 (fused): blocks 0..31 -> Wc = W2@W1 (16x512); block 32 -> cconst;
// blocks 33.. -> supertile degree histogram (LDS-binned, no global atomics).
// ---------------------------------------------------------------------------
__global__ __launch_bounds__(256) void prep_hist_kernel(
        const float* __restrict__ W1, const float* __restrict__ b1,
        const float* __restrict__ W2, const float* __restrict__ b2,
        float* __restrict__ Wc, float* __restrict__ cconst,
        const int* __restrict__ ei, int* __restrict__ phist, int E) {
    __shared__ int h[STILE];
    if (blockIdx.x < 32) {
        int idx = blockIdx.x * 256 + threadIdx.x;   // 0 .. 8191
        int o = idx >> 9;
        int k = idx & 511;
        float s = 0.f;
#pragma unroll 8
        for (int hh = 0; hh < HID_C; ++hh)
            s = fmaf(W2[o * HID_C + hh], W1[hh * IN_C + k], s);
        Wc[o * IN_C + k] = s;
        return;
    }
    if (blockIdx.x == 32) {
        if (threadIdx.x < OUT_C) {
            int o = threadIdx.x;
            float s = b2[o];
            for (int hh = 0; hh < HID_C; ++hh)
                s = fmaf(b1[hh], W2[o * HID_C + hh], s);
            cconst[o] = s;
        }
        return;
    }
    const int hb = blockIdx.x - 33;
    const int st = hb / KCH_H;
    const int k = hb - st * KCH_H;
    for (int i = threadIdx.x; i < STILE; i += 256) h[i] = 0;
    __syncthreads();

    const int chunk = (((E + KCH_H - 1) / KCH_H) + 3) & ~3;
    const int beg = k * chunk;
    const int end = min(E, beg + chunk);
    const int* cols = ei + E;

    const int nv = (end > beg) ? ((end - beg) >> 2) : 0;
    const i32x4* cv = (const i32x4*)(cols + beg);
    for (int i = threadIdx.x; i < nv; i += 256) {
        i32x4 c = cv[i];
#pragma unroll
        for (int j = 0; j < 4; ++j) {
            int cj = c[j];
            if ((cj >> SSH) == st) atomicAdd(&h[cj & (STILE - 1)], 1);
        }
    }
    for (int e = beg + (nv << 2) + threadIdx.x; e < end; e += 256) {
        int cj = cols[e];
        if ((cj >> SSH) == st) atomicAdd(&h[cj & (STILE - 1)], 1);
    }
    __syncthreads();
    int* outp = phist + (size_t)hb * STILE;   // layout [st][k][i]
    for (int i = threadIdx.x; i < STILE; i += 256) outp[i] = h[i];
}

// ---------------------------------------------------------------------------
// K2: dsq[n] = sqrt(sum_k phist); zero all NREP f16 agg replicas.
// ---------------------------------------------------------------------------
__global__ void dsq_zero_kernel(const int* __restrict__ phist, float* __restrict__ dsq,
                                unsigned int* __restrict__ agg32, int N, int zeroWords) {
    int i = blockIdx.x * 256 + threadIdx.x;
    if (i < N) {
        int st = i >> SSH, ii = i & (STILE - 1);
        const int* p = phist + (size_t)st * KCH_H * STILE + ii;
        int s = 0;
#pragma unroll
        for (int k = 0; k < KCH_H; ++k) s += p[k * STILE];
        dsq[i] = sqrtf((float)s);
    }
    if (i < zeroWords) agg32[i] = 0u;
}

// ---------------------------------------------------------------------------
// K3: h2h[r][o] = (f16)( dsq[r] * (x[r] @ Wc^T)[o] ).
// Wc in LDS (32KB); each wave processes 4 rows/iter.
// ---------------------------------------------------------------------------
__global__ __launch_bounds__(256) void h2_kernel(const float* __restrict__ x,
                                                 const float* __restrict__ WcG,
                                                 const float* __restrict__ dsq,
                                                 _Float16* __restrict__ h2h, int N) {
    __shared__ float wl[16 * IN_C];
    for (int i = threadIdx.x; i < (16 * IN_C) / 4; i += 256)
        ((f32x4*)wl)[i] = ((const f32x4*)WcG)[i];
    __syncthreads();

    const int lane = threadIdx.x & 63;
    const int wid = (blockIdx.x * 256 + threadIdx.x) >> 6;
    const int nw  = (gridDim.x * 256) >> 6;

    for (int r0 = wid * 4; r0 < N; r0 += nw * 4) {
        const int rmax = min(4, N - r0);
        f32x4 a0[4], a1[4];
#pragma unroll
        for (int rr = 0; rr < 4; ++rr) {
            int r = r0 + (rr < rmax ? rr : 0);
            a0[rr] = *(const f32x4*)(x + (size_t)r * IN_C + 4 * lane);
            a1[rr] = *(const f32x4*)(x + (size_t)r * IN_C + 256 + 4 * lane);
        }
        float p[4][16];
#pragma unroll
        for (int oo = 0; oo < 16; ++oo) {
            f32x4 w0 = *(const f32x4*)(wl + oo * IN_C + 4 * lane);
            f32x4 w1 = *(const f32x4*)(wl + oo * IN_C + 256 + 4 * lane);
#pragma unroll
            for (int rr = 0; rr < 4; ++rr) {
                float s = a0[rr].x * w0.x;
                s = fmaf(a0[rr].y, w0.y, s);
                s = fmaf(a0[rr].z, w0.z, s);
                s = fmaf(a0[rr].w, w0.w, s);
                s = fmaf(a1[rr].x, w1.x, s);
                s = fmaf(a1[rr].y, w1.y, s);
                s = fmaf(a1[rr].z, w1.z, s);
                s = fmaf(a1[rr].w, w1.w, s);
                p[rr][oo] = s;
            }
        }
        float v[4];
#pragma unroll
        for (int rr = 0; rr < 4; ++rr) {
#define RSTEP(MASK, HALF)                                              \
            {                                                          \
                const bool hi = (lane & MASK) != 0;                    \
                _Pragma("unroll")                                      \
                for (int ii = 0; ii < HALF; ++ii) {                    \
                    float send = hi ? p[rr][ii] : p[rr][ii + HALF];    \
                    float recv = __shfl_xor(send, MASK, 64);           \
                    float keep = hi ? p[rr][ii + HALF] : p[rr][ii];    \
                    p[rr][ii] = keep + recv;                           \
                }                                                      \
            }
            RSTEP(1, 8)
            RSTEP(2, 4)
            RSTEP(4, 2)
            RSTEP(8, 1)
#undef RSTEP
            v[rr] = p[rr][0];
        }
        const bool h16 = (lane & 16) != 0;
        float sA = h16 ? v[0] : v[1];
        float mA = (h16 ? v[1] : v[0]) + __shfl_xor(sA, 16, 64);
        float sB = h16 ? v[2] : v[3];
        float mB = (h16 ? v[3] : v[2]) + __shfl_xor(sB, 16, 64);
        const bool h32 = (lane & 32) != 0;
        float sC = h32 ? mA : mB;
        float f  = (h32 ? mB : mA) + __shfl_xor(sC, 32, 64);
        const int qq = lane >> 4, jj = lane & 15;
        const int oo = ((jj & 1) << 3) | ((jj & 2) << 1) | ((jj & 4) >> 1) | ((jj & 8) >> 3);
        if (qq < rmax) {
            int r = r0 + qq;
            h2h[(size_t)r * OUT_C + oo] = (_Float16)(f * dsq[r]);
        }
    }
}

// ---------------------------------------------------------------------------
// K4: edge scatter into the XCD-local replica. 8 lanes/edge; replica chosen
// by blockIdx&7 (matches round-robin block->XCD dispatch), so each replica's
// lines stay resident in one XCD's L2 and atomic RMW resolves locally
// instead of ping-ponging through the shared coherence point.
// ---------------------------------------------------------------------------
__global__ __launch_bounds__(256) void edge_kernel(const int* __restrict__ ei,
                                                   const _Float16* __restrict__ h2h,
                                                   h16x2* __restrict__ agg,
                                                   int E, int aggWords) {
    h16x2* aggR = agg + (size_t)(blockIdx.x & (NREP - 1)) * aggWords;
    int t = blockIdx.x * 256 + threadIdx.x;
    int e = t >> 3;
    if (e >= E) return;
    int op = t & 7;                       // half2 pair: outputs 2op, 2op+1
    int r = ei[e];
    int c = ei[E + e];
    h16x2 h = *(const h16x2*)(h2h + (size_t)r * OUT_C + (op << 1));
    pk_atomic_add_f16(&aggR[(size_t)c * 8 + op], h);
}

// ---------------------------------------------------------------------------
// K5: finalize: out[n][o] = cconst[o] + dsq[n] * sum_rep (float)agg[rep][n][o]
// (f32 merge of the 8 f16 replicas -> slightly better precision too)
// ---------------------------------------------------------------------------
__global__ void final_kernel(const h16x2* __restrict__ agg, const float* __restrict__ dsq,
                             const float* __restrict__ cconst, float* __restrict__ out,
                             int words, int aggWords) {
    int i = blockIdx.x * 256 + threadIdx.x;
    if (i >= words) return;
    int n = i >> 3;
    int o = (i & 7) << 1;
    float sx = 0.f, sy = 0.f;
#pragma unroll
    for (int rep = 0; rep < NREP; ++rep) {
        h16x2 a = agg[(size_t)rep * aggWords + i];
        sx += (float)a.x;
        sy += (float)a.y;
    }
    float d = dsq[n];
    f32x2 r;
    r.x = fmaf(d, sx, cconst[o]);
    r.y = fmaf(d, sy, cconst[o + 1]);
    *(f32x2*)(out + ((size_t)i << 1)) = r;
}

// ---------------------------------------------------------------------------
extern "C" void kernel_launch(void* const* d_in, const int* in_sizes, int n_in,
                              void* d_out, int out_size, void* d_ws, size_t ws_size,
                              hipStream_t stream) {
    const float* x  = (const float*)d_in[0];
    const int*   ei = (const int*)d_in[1];
    const float* W1 = (const float*)d_in[2];
    const float* b1 = (const float*)d_in[3];
    const float* W2 = (const float*)d_in[4];
    const float* b2 = (const float*)d_in[5];
    float* out = (float*)d_out;

    const int N = in_sizes[0] / IN_C;    // 50000
    const int E = in_sizes[1] / 2;       // 800000
    const int ST = (N + STILE - 1) / STILE;      // 7
    const int aggWords = (N * OUT_C) / 2;        // 400000 h16x2 words per replica
    const int zeroWords = NREP * aggWords;       // 3.2M words = 12.8MB

    // workspace (4-byte units):
    // Wc[8192] | cconst[16] | dsq[N] | h2h[8N words] | phist[ST*KCH_H*STILE] | agg[NREP*aggWords]
    float* ws     = (float*)d_ws;
    float* Wc     = ws;
    float* cconst = ws + 16 * IN_C;
    float* dsq    = cconst + 16;
    _Float16* h2h = (_Float16*)(dsq + N);                 // N*16 halves
    int*   phist  = (int*)((unsigned int*)(dsq + N) + 8 * (size_t)N);
    unsigned int* agg32 = (unsigned int*)(phist + (size_t)ST * KCH_H * STILE);
    h16x2* agg = (h16x2*)agg32;
    // total ~ 18.3 MB

    hipLaunchKernelGGL(prep_hist_kernel, dim3(33 + ST * KCH_H), dim3(256), 0, stream,
                       W1, b1, W2, b2, Wc, cconst, ei, phist, E);
    hipLaunchKernelGGL(dsq_zero_kernel, dim3((zeroWords + 255) / 256), dim3(256), 0, stream,
                       phist, dsq, agg32, N, zeroWords);
    hipLaunchKernelGGL(h2_kernel, dim3(768), dim3(256), 0, stream, x, Wc, dsq, h2h, N);
    hipLaunchKernelGGL(edge_kernel, dim3((E * 8 + 255) / 256), dim3(256), 0, stream,
                       ei, h2h, agg, E, aggWords);
    hipLaunchKernelGGL(final_kernel, dim3((N * OUT_C / 2 + 255) / 256), dim3(256), 0, stream,
                       agg, dsq, cconst, out, N * OUT_C / 2, aggWords);
}

// Round 16
// 90.842 us; speedup vs baseline: 1.2164x; 1.2164x over previous
//
#include <hip/hip_runtime.h>
#include <hip/hip_bf16.h>
#include <hip/hip_fp16.h>

#define IN_C 512
#define HID_C 128
#define OUT_C 16
#define STILE 8192     // nodes per hist supertile (32KB LDS)
#define SSH  13        // log2(STILE)
#define KCH_H 32       // edge chunks per supertile (hist)

typedef float    f32x4 __attribute__((ext_vector_type(4)));
typedef float    f32x2 __attribute__((ext_vector_type(2)));
typedef int      i32x4 __attribute__((ext_vector_type(4)));
typedef _Float16 h16x2 __attribute__((ext_vector_type(2)));

// Packed f16 global atomic add (global_atomic_pk_add_f16 on CDNA).
__device__ inline void pk_atomic_add_f16(h16x2* addr, h16x2 val) {
#if __has_builtin(__builtin_amdgcn_global_atomic_fadd_v2f16)
    __builtin_amdgcn_global_atomic_fadd_v2f16(addr, val);
#else
    unsigned int* ap = (unsigned int*)addr;
    unsigned int old = *ap, assumed;
    do {
        assumed = old;
        h16x2 cur = __builtin_bit_cast(h16x2, assumed);
        h16x2 nv = cur + val;
        old = atomicCAS(ap, assumed, __builtin_bit_cast(unsigned int, nv));
    } while (old != assumed);
#endif
}

// ---------------------------------------------------------------------------
// K1 (fused): blocks 0..31 -> Wc = W2@W1; block 32 -> cconst;
// blocks 33..32+ST*KCH_H -> supertile degree histogram (LDS-binned);
// remaining blocks -> zero the f16 agg buffer.
// ---------------------------------------------------------------------------
__global__ __launch_bounds__(256) void prep_hist_kernel(
        const float* __restrict__ W1, const float* __restrict__ b1,
        const float* __restrict__ W2, const float* __restrict__ b2,
        float* __restrict__ Wc, float* __restrict__ cconst,
        const int* __restrict__ ei, int* __restrict__ phist,
        unsigned int* __restrict__ agg32, int E, int nhist, int aggWords) {
    __shared__ int h[STILE];
    if (blockIdx.x < 32) {
        int idx = blockIdx.x * 256 + threadIdx.x;   // 0 .. 8191
        int o = idx >> 9;
        int k = idx & 511;
        float s = 0.f;
#pragma unroll 8
        for (int hh = 0; hh < HID_C; ++hh)
            s = fmaf(W2[o * HID_C + hh], W1[hh * IN_C + k], s);
        Wc[o * IN_C + k] = s;
        return;
    }
    if (blockIdx.x == 32) {
        if (threadIdx.x < OUT_C) {
            int o = threadIdx.x;
            float s = b2[o];
            for (int hh = 0; hh < HID_C; ++hh)
                s = fmaf(b1[hh], W2[o * HID_C + hh], s);
            cconst[o] = s;
        }
        return;
    }
    if (blockIdx.x >= 33 + nhist) {
        // agg zeroing
        int i = (blockIdx.x - 33 - nhist) * 256 + threadIdx.x;
        if (i < aggWords) agg32[i] = 0u;
        return;
    }
    const int hb = blockIdx.x - 33;
    const int st = hb / KCH_H;
    const int k = hb - st * KCH_H;
    for (int i = threadIdx.x; i < STILE; i += 256) h[i] = 0;
    __syncthreads();

    const int chunk = (((E + KCH_H - 1) / KCH_H) + 3) & ~3;
    const int beg = k * chunk;
    const int end = min(E, beg + chunk);
    const int* cols = ei + E;

    const int nv = (end > beg) ? ((end - beg) >> 2) : 0;
    const i32x4* cv = (const i32x4*)(cols + beg);
    for (int i = threadIdx.x; i < nv; i += 256) {
        i32x4 c = cv[i];
#pragma unroll
        for (int j = 0; j < 4; ++j) {
            int cj = c[j];
            if ((cj >> SSH) == st) atomicAdd(&h[cj & (STILE - 1)], 1);
        }
    }
    for (int e = beg + (nv << 2) + threadIdx.x; e < end; e += 256) {
        int cj = cols[e];
        if ((cj >> SSH) == st) atomicAdd(&h[cj & (STILE - 1)], 1);
    }
    __syncthreads();
    int* outp = phist + (size_t)hb * STILE;   // layout [st][k][i]
    for (int i = threadIdx.x; i < STILE; i += 256) outp[i] = h[i];
}

// ---------------------------------------------------------------------------
// K2: h2h[r][o] = (f16)( dsq[r] * (x[r] @ Wc^T)[o] ), dsq computed inline
// from phist (2 L2 loads/lane + 16-lane shuffle reduce per 4-row group)
// and stored for final_kernel. Wc in LDS; 4 rows/wave/iter.
// ---------------------------------------------------------------------------
__global__ __launch_bounds__(256) void h2_kernel(const float* __restrict__ x,
                                                 const float* __restrict__ WcG,
                                                 const int* __restrict__ phist,
                                                 float* __restrict__ dsq,
                                                 _Float16* __restrict__ h2h, int N) {
    __shared__ float wl[16 * IN_C];
    for (int i = threadIdx.x; i < (16 * IN_C) / 4; i += 256)
        ((f32x4*)wl)[i] = ((const f32x4*)WcG)[i];
    __syncthreads();

    const int lane = threadIdx.x & 63;
    const int wid = (blockIdx.x * 256 + threadIdx.x) >> 6;
    const int nw  = (gridDim.x * 256) >> 6;

    for (int r0 = wid * 4; r0 < N; r0 += nw * 4) {
        const int rmax = min(4, N - r0);

        // ---- inline dsq for rows r0..r0+3: lane l covers row (l>>4), k=(l&15) and (l&15)+16
        const int rr_d = lane >> 4;
        const int rd = min(r0 + rr_d, N - 1);
        const int std = rd >> SSH, id = rd & (STILE - 1);
        const int kd = lane & 15;
        const int* pb = phist + ((size_t)std * KCH_H) * STILE + id;
        int deg = pb[(size_t)kd * STILE] + pb[(size_t)(kd + 16) * STILE];
        deg += __shfl_xor(deg, 1, 64);
        deg += __shfl_xor(deg, 2, 64);
        deg += __shfl_xor(deg, 4, 64);
        deg += __shfl_xor(deg, 8, 64);
        const float dsq_r = sqrtf((float)deg);       // per-lane: dsq of row r0+(lane>>4)
        if (kd == 0 && rr_d < rmax) dsq[r0 + rr_d] = dsq_r;

        f32x4 a0[4], a1[4];
#pragma unroll
        for (int rr = 0; rr < 4; ++rr) {
            int r = r0 + (rr < rmax ? rr : 0);
            a0[rr] = *(const f32x4*)(x + (size_t)r * IN_C + 4 * lane);
            a1[rr] = *(const f32x4*)(x + (size_t)r * IN_C + 256 + 4 * lane);
        }
        float p[4][16];
#pragma unroll
        for (int oo = 0; oo < 16; ++oo) {
            f32x4 w0 = *(const f32x4*)(wl + oo * IN_C + 4 * lane);
            f32x4 w1 = *(const f32x4*)(wl + oo * IN_C + 256 + 4 * lane);
#pragma unroll
            for (int rr = 0; rr < 4; ++rr) {
                float s = a0[rr].x * w0.x;
                s = fmaf(a0[rr].y, w0.y, s);
                s = fmaf(a0[rr].z, w0.z, s);
                s = fmaf(a0[rr].w, w0.w, s);
                s = fmaf(a1[rr].x, w1.x, s);
                s = fmaf(a1[rr].y, w1.y, s);
                s = fmaf(a1[rr].z, w1.z, s);
                s = fmaf(a1[rr].w, w1.w, s);
                p[rr][oo] = s;
            }
        }
        float v[4];
#pragma unroll
        for (int rr = 0; rr < 4; ++rr) {
#define RSTEP(MASK, HALF)                                              \
            {                                                          \
                const bool hi = (lane & MASK) != 0;                    \
                _Pragma("unroll")                                      \
                for (int ii = 0; ii < HALF; ++ii) {                    \
                    float send = hi ? p[rr][ii] : p[rr][ii + HALF];    \
                    float recv = __shfl_xor(send, MASK, 64);           \
                    float keep = hi ? p[rr][ii + HALF] : p[rr][ii];    \
                    p[rr][ii] = keep + recv;                           \
                }                                                      \
            }
            RSTEP(1, 8)
            RSTEP(2, 4)
            RSTEP(4, 2)
            RSTEP(8, 1)
#undef RSTEP
            v[rr] = p[rr][0];
        }
        const bool h16 = (lane & 16) != 0;
        float sA = h16 ? v[0] : v[1];
        float mA = (h16 ? v[1] : v[0]) + __shfl_xor(sA, 16, 64);
        float sB = h16 ? v[2] : v[3];
        float mB = (h16 ? v[3] : v[2]) + __shfl_xor(sB, 16, 64);
        const bool h32 = (lane & 32) != 0;
        float sC = h32 ? mA : mB;
        float f  = (h32 ? mB : mA) + __shfl_xor(sC, 32, 64);
        const int qq = lane >> 4, jj = lane & 15;
        const int oo = ((jj & 1) << 3) | ((jj & 2) << 1) | ((jj & 4) >> 1) | ((jj & 8) >> 3);
        if (qq < rmax) {
            int r = r0 + qq;
            h2h[(size_t)r * OUT_C + oo] = (_Float16)(f * dsq_r);
        }
    }
}

// ---------------------------------------------------------------------------
// K3: edge scatter (exact R14 form — proven). 8 lanes/edge, one h16x2 load
// + one pk-f16 atomic per lane.
// ---------------------------------------------------------------------------
__global__ __launch_bounds__(256) void edge_kernel(const int* __restrict__ ei,
                                                   const _Float16* __restrict__ h2h,
                                                   h16x2* __restrict__ agg, int E) {
    int t = blockIdx.x * 256 + threadIdx.x;
    int e = t >> 3;
    if (e >= E) return;
    int op = t & 7;                       // half2 pair: outputs 2op, 2op+1
    int r = ei[e];
    int c = ei[E + e];
    h16x2 h = *(const h16x2*)(h2h + (size_t)r * OUT_C + (op << 1));
    pk_atomic_add_f16(&agg[(size_t)c * 8 + op], h);
}

// ---------------------------------------------------------------------------
// K4: finalize: out[n][o] = cconst[o] + dsq[n] * (float)agg[n][o]
// ---------------------------------------------------------------------------
__global__ void final_kernel(const h16x2* __restrict__ agg, const float* __restrict__ dsq,
                             const float* __restrict__ cconst, float* __restrict__ out,
                             int words) {
    int i = blockIdx.x * 256 + threadIdx.x;
    if (i >= words) return;
    int n = i >> 3;
    int o = (i & 7) << 1;
    h16x2 a = agg[i];
    float d = dsq[n];
    f32x2 r;
    r.x = fmaf(d, (float)a.x, cconst[o]);
    r.y = fmaf(d, (float)a.y, cconst[o + 1]);
    *(f32x2*)(out + ((size_t)i << 1)) = r;
}

// ---------------------------------------------------------------------------
extern "C" void kernel_launch(void* const* d_in, const int* in_sizes, int n_in,
                              void* d_out, int out_size, void* d_ws, size_t ws_size,
                              hipStream_t stream) {
    const float* x  = (const float*)d_in[0];
    const int*   ei = (const int*)d_in[1];
    const float* W1 = (const float*)d_in[2];
    const float* b1 = (const float*)d_in[3];
    const float* W2 = (const float*)d_in[4];
    const float* b2 = (const float*)d_in[5];
    float* out = (float*)d_out;

    const int N = in_sizes[0] / IN_C;    // 50000
    const int E = in_sizes[1] / 2;       // 800000
    const int ST = (N + STILE - 1) / STILE;      // 7
    const int nhist = ST * KCH_H;                // 224
    const int aggWords = (N * OUT_C) / 2;        // 400000 h16x2 words

    // workspace (4-byte units):
    // Wc[8192] | cconst[16] | dsq[N] | h2h[8N words] | phist[ST*KCH_H*STILE] | agg[aggWords]
    float* ws     = (float*)d_ws;
    float* Wc     = ws;
    float* cconst = ws + 16 * IN_C;
    float* dsq    = cconst + 16;
    _Float16* h2h = (_Float16*)(dsq + N);                 // N*16 halves
    int*   phist  = (int*)((unsigned int*)(dsq + N) + 8 * (size_t)N);
    unsigned int* agg32 = (unsigned int*)(phist + (size_t)ST * KCH_H * STILE);
    h16x2* agg = (h16x2*)agg32;
    // total ~ 13 MB

    const int zblocks = (aggWords + 255) / 256;   // 1563
    hipLaunchKernelGGL(prep_hist_kernel, dim3(33 + nhist + zblocks), dim3(256), 0, stream,
                       W1, b1, W2, b2, Wc, cconst, ei, phist, agg32, E, nhist, aggWords);
    hipLaunchKernelGGL(h2_kernel, dim3(1024), dim3(256), 0, stream, x, Wc, phist, dsq, h2h, N);
    hipLaunchKernelGGL(edge_kernel, dim3((E * 8 + 255) / 256), dim3(256), 0, stream,
                       ei, h2h, agg, E);
    hipLaunchKernelGGL(final_kernel, dim3((aggWords + 255) / 256), dim3(256), 0, stream,
                       agg, dsq, cconst, out, aggWords);
}